// Round 4
// baseline (132.432 us; speedup 1.0000x reference)
//
#include <hip/hip_runtime.h>
#include <hip/hip_bf16.h>
#include <stdint.h>

// ---- problem constants ----
#define M_TOT 12288   // B*T = 48*256
#define K_DIM 1024
#define N_DIM 1024
#define NTILE 16      // K_DIM / 64

// GEMM geometry: BM=192, BN=256, BK=64, 8 waves (2M x 4N), grid 64x4=256 blocks
#define LDSBUF 57344  // per-buffer bytes: A 24576 (bf16) + B 2x16384

typedef __attribute__((ext_vector_type(8))) __bf16 bf16x8;
typedef __attribute__((ext_vector_type(4))) __bf16 bf16x4;
typedef __attribute__((ext_vector_type(4))) float  f32x4;

// ---------------------------------------------------------------------------
// Kernel 1: W[do][di] = sum_r H[r,k,s] * B[r,j,i],  do=k*32+j, di=s*32+i
// ---------------------------------------------------------------------------
__global__ __launch_bounds__(256)
void make_w(const float* __restrict__ A4,   // [8][4][8][8]
            const float* __restrict__ Bs,   // [8][32][32]
            __bf16* __restrict__ W)         // [1024][1024], di contiguous
{
    int idx = blockIdx.x * 256 + threadIdx.x;
    int dout = idx >> 10;
    int din  = idx & 1023;
    int k = dout >> 5, j = dout & 31;
    int s = din  >> 5, i = din  & 31;
    int kb = k >> 3, k8 = k & 7;
    int sb = s >> 3, s8 = s & 7;

    const int   comp[4][4] = {{0,1,2,3},{1,0,3,2},{2,3,0,1},{3,2,1,0}};
    const float sgn [4][4] = {{1.f,-1.f,-1.f,-1.f},
                              {1.f, 1.f,-1.f, 1.f},
                              {1.f, 1.f, 1.f,-1.f},
                              {1.f,-1.f, 1.f, 1.f}};
    int   c  = comp[kb][sb];
    float sg = sgn [kb][sb];

    float acc = 0.f;
    #pragma unroll
    for (int r = 0; r < 8; ++r) {
        float h = A4[((r*4 + c)*8 + k8)*8 + s8];
        float b = Bs[(r*32 + j)*32 + i];
        acc += h * b;
    }
    W[idx] = (__bf16)(sg * acc);
}

// ---------------------------------------------------------------------------
// Kernel 2: 192x256-tile 8-phase GEMM with FUSED f32->bf16 A-staging.
// C[M][N] = x[M][K](f32) * W[N][K]^T + bias  (f32 out)
// A path (T14 reg-staging): 6 global_load_dwordx4 (f32) issued one tile
//   ahead -> vmcnt(4) -> cvt to bf16 -> 6 ds_write_b64 at swizzled address.
// B path: global_load_lds with pre-unswizzled source (linear LDS dest).
// LDS per buffer: [A 24K bf16 rows 0..191][B-nh0 16K][B-nh1 16K]
// Rows 128 B; elem(row,colb) at row*128 + (colb ^ ((row&7)<<4)).
// Phases: PH0=(sub0,nh0) PH1=(sub0,nh1) PH2=(sub1,nh1) PH3=(sub1,nh0).
// vmcnt ledger (steady, per tile): A(t+1)x6 oldest, B(t+1)x4 newer,
//   then A(t+2)x6; PH3 vmcnt(4) drains A(t+1); tile-end vmcnt(6) drains
//   B(t+1), keeps A(t+2) in flight. Never vmcnt(0) until the tail.
// ---------------------------------------------------------------------------
__device__ __forceinline__ void gl_lds16(const void* g, void* l)
{
    __builtin_amdgcn_global_load_lds(
        (const __attribute__((address_space(1))) void*)g,
        (__attribute__((address_space(3))) void*)l,
        16, 0, 0);
}

#define PHASE_MFMA(SUB, NH, BF)                                                 \
    __builtin_amdgcn_s_barrier();                                               \
    asm volatile("s_waitcnt lgkmcnt(0)" ::: "memory");                          \
    __builtin_amdgcn_sched_barrier(0);                                          \
    __builtin_amdgcn_s_setprio(1);                                              \
    _Pragma("unroll")                                                           \
    for (int mi = 0; mi < 3; ++mi) {                                            \
        _Pragma("unroll")                                                       \
        for (int ni = 0; ni < 2; ++ni) {                                        \
            acc[(SUB)*3+mi][(NH)*2+ni] = __builtin_amdgcn_mfma_f32_16x16x32_bf16(\
                aF[mi][0], BF[ni][0], acc[(SUB)*3+mi][(NH)*2+ni], 0, 0, 0);     \
            acc[(SUB)*3+mi][(NH)*2+ni] = __builtin_amdgcn_mfma_f32_16x16x32_bf16(\
                aF[mi][1], BF[ni][1], acc[(SUB)*3+mi][(NH)*2+ni], 0, 0, 0);     \
        }                                                                       \
    }                                                                           \
    __builtin_amdgcn_s_setprio(0);                                              \
    __builtin_amdgcn_s_barrier();

__global__ __launch_bounds__(512, 2)
void gemm8p(const float* __restrict__ X,    // [M][1024] f32
            const __bf16* __restrict__ BT,  // [1024][1024]  (W)
            const float*  __restrict__ bias,
            float* __restrict__ C)          // [M][1024]
{
    __shared__ __align__(16) char lds[2 * LDSBUF];

    const int tid  = threadIdx.x;
    const int wave = tid >> 6;
    const int lane = tid & 63;

    // bijective XCD swizzle (256 % 8 == 0)
    int wg  = blockIdx.x;
    int swz = (wg & 7) * 32 + (wg >> 3);
    const int brow = (swz >> 2) * 192;   // 64 M-tiles
    const int bcol = (swz & 3)  * 256;   // 4  N-tiles

    const int mg = wave >> 2;    // m-group 0/1 (rows mg*96..+95)
    const int ng = wave & 3;     // n-group 0..3 (cols ng*64..+63)
    const int fr = lane & 15;
    const int kq = lane >> 4;

    f32x4 acc[6][4];
    #pragma unroll
    for (int i = 0; i < 6; ++i)
        #pragma unroll
        for (int j = 0; j < 4; ++j)
            acc[i][j] = (f32x4){0.f, 0.f, 0.f, 0.f};

    float4 aPre[3][2];   // in-flight A f32 (one tile ahead)

    // ---- A: issue 6 f32 dwordx4 loads for tile ta into aPre ----
    auto loadA = [&](int ta) {
        if (ta >= NTILE) return;
        #pragma unroll
        for (int c = 0; c < 3; ++c) {
            #pragma unroll
            for (int p = 0; p < 2; ++p) {
                int s   = c * 16384 + p * 8192 + tid * 16;  // byte in 192x256B tile
                int row = s >> 8;
                const float* src = X + (size_t)(brow + row) * K_DIM
                                     + ta * 64 + ((s & 255) >> 2);
                aPre[c][p] = *(const float4*)src;
            }
        }
    };
    // ---- A: cvt + ds_write_b64 into swizzled layout of buf[ta&1] ----
    auto writeA = [&](int ta) {
        if (ta >= NTILE) return;
        char* region = lds + (ta & 1) * LDSBUF;
        #pragma unroll
        for (int c = 0; c < 3; ++c) {
            #pragma unroll
            for (int p = 0; p < 2; ++p) {
                int sb   = c * 8192 + p * 4096 + tid * 8;   // bf16-byte offset
                int row  = sb >> 7;
                int colb = (sb & 127) ^ ((row & 7) << 4);
                float4 f = aPre[c][p];
                bf16x4 v;
                v[0] = (__bf16)f.x; v[1] = (__bf16)f.y;
                v[2] = (__bf16)f.z; v[3] = (__bf16)f.w;
                *(bf16x4*)(region + row * 128 + colb) = v;
            }
        }
    };
    // ---- B: gl_lds, 2 x 16B per thread per half ----
    auto stageB = [&](int ta, int nh) {
        if (ta >= NTILE) return;
        char* region = lds + (ta & 1) * LDSBUF + 24576 + nh * 16384;
        #pragma unroll
        for (int q = 0; q < 2; ++q) {
            int s    = q * 8192 + tid * 16;
            int rwh  = s >> 7;                            // 0..127
            int colb = (s & 127) ^ ((rwh & 7) << 4);      // inverse swizzle
            int absr = ((rwh >> 5) << 6) + nh * 32 + (rwh & 31);
            const char* src = (const char*)BT +
                ((size_t)(bcol + absr) * K_DIM + ta * 64) * 2 + colb;
            gl_lds16(src, region + q * 8192 + wave * 1024);
        }
    };

    bf16x8 aF[3][2], bF0[2][2], bF1[2][2];

    auto ldA = [&](int bufb, int sub) {
        const char* base = lds + bufb;
        #pragma unroll
        for (int mi = 0; mi < 3; ++mi) {
            int rwh = mg * 96 + sub * 48 + mi * 16 + fr;
            #pragma unroll
            for (int ks = 0; ks < 2; ++ks) {
                int col = (ks * 64 + kq * 16) ^ ((rwh & 7) << 4);
                aF[mi][ks] = *(const bf16x8*)(base + rwh * 128 + col);
            }
        }
    };
    auto ldB = [&](bf16x8 (&bF)[2][2], int bufb, int nh) {
        const char* base = lds + bufb + 24576 + nh * 16384;
        #pragma unroll
        for (int ni = 0; ni < 2; ++ni) {
            int rwh = ng * 32 + ni * 16 + fr;
            #pragma unroll
            for (int ks = 0; ks < 2; ++ks) {
                int col = (ks * 64 + kq * 16) ^ ((rwh & 7) << 4);
                bF[ni][ks] = *(const bf16x8*)(base + rwh * 128 + col);
            }
        }
    };

    // ---- prologue ----
    loadA(0);                        // A0 x6
    stageB(0, 0); stageB(0, 1);      // B0 x4
    asm volatile("s_waitcnt vmcnt(4)" ::: "memory");   // A0 done (B0 remains)
    writeA(0);
    loadA(1);                        // A1 x6 in flight
    asm volatile("s_waitcnt vmcnt(6) lgkmcnt(0)" ::: "memory"); // drain B0 + A0 writes
    __builtin_amdgcn_s_barrier();

    // ---- main loop: 16 K-tiles x 4 phases ----
    for (int t = 0; t < NTILE; ++t) {
        const int bufb = (t & 1) * LDSBUF;

        // PH0: (sub0, nh0)
        ldA(bufb, 0);
        ldB(bF0, bufb, 0);
        stageB(t + 1, 0);
        PHASE_MFMA(0, 0, bF0)

        // PH1: (sub0, nh1)
        ldB(bF1, bufb, 1);
        stageB(t + 1, 1);
        PHASE_MFMA(0, 1, bF1)

        // PH2: (sub1, nh1) — reuse bF1
        ldA(bufb, 1);
        PHASE_MFMA(1, 1, bF1)

        // PH3: (sub1, nh0) — reg-reuse MFMA; A write-late + next prefetch
        if (t + 1 < NTILE) {
            asm volatile("s_waitcnt vmcnt(4)" ::: "memory");  // A(t+1) landed
            writeA(t + 1);
            loadA(t + 2);
        }
        __builtin_amdgcn_s_barrier();
        __builtin_amdgcn_s_setprio(1);
        #pragma unroll
        for (int mi = 0; mi < 3; ++mi) {
            #pragma unroll
            for (int ni = 0; ni < 2; ++ni) {
                acc[3+mi][ni] = __builtin_amdgcn_mfma_f32_16x16x32_bf16(
                    aF[mi][0], bF0[ni][0], acc[3+mi][ni], 0, 0, 0);
                acc[3+mi][ni] = __builtin_amdgcn_mfma_f32_16x16x32_bf16(
                    aF[mi][1], bF0[ni][1], acc[3+mi][ni], 0, 0, 0);
            }
        }
        __builtin_amdgcn_s_setprio(0);
        // counted drain: B(t+1) done + A-writes visible; A(t+2) stays in flight
        if (t < NTILE - 2) {
            asm volatile("s_waitcnt vmcnt(6) lgkmcnt(0)" ::: "memory");
        } else {
            asm volatile("s_waitcnt vmcnt(0) lgkmcnt(0)" ::: "memory");
        }
        __builtin_amdgcn_s_barrier();
    }

    // ---- epilogue ----
    #pragma unroll
    for (int mf = 0; mf < 6; ++mf) {
        int r0 = brow + mg * 96 + mf * 16 + kq * 4;
        #pragma unroll
        for (int nf = 0; nf < 4; ++nf) {
            int c0 = bcol + ng * 64 + nf * 16 + fr;
            float bv = bias[c0];
            #pragma unroll
            for (int j = 0; j < 4; ++j)
                C[(size_t)(r0 + j) * N_DIM + c0] = acc[mf][nf][j] + bv;
        }
    }
}

// ---------------------------------------------------------------------------
extern "C" void kernel_launch(void* const* d_in, const int* in_sizes, int n_in,
                              void* d_out, int out_size, void* d_ws, size_t ws_size,
                              hipStream_t stream)
{
    const float* x    = (const float*)d_in[0];   // [48][256][1024]
    const float* A4   = (const float*)d_in[1];   // [8][4][8][8]
    const float* Bs   = (const float*)d_in[2];   // [8][32][32]
    const float* bias = (const float*)d_in[3];   // [1024]
    float* out = (float*)d_out;

    __bf16* W = (__bf16*)d_ws;                   // 2 MB

    make_w<<<4096, 256, 0, stream>>>(A4, Bs, W);
    gemm8p<<<256, 512, 0, stream>>>(x, W, bias, out);
}